// Round 5
// baseline (274.345 us; speedup 1.0000x reference)
//
#include <hip/hip_runtime.h>

#define B_SZ    16
#define T_LEN   1024
#define C_CH    32
#define TC      (T_LEN * C_CH)      // 32768
#define S_MAIN  128
#define NB_P    400
#define P_TOP   60
#define OUT_CH  (NB_P + P_TOP)      // 460
#define NGROUP  8                   // 8 groups x 2 batches
#define CHUNK   256                 // pairs per block
#define NBLK_M  (S_MAIN * NB_P / CHUNK)   // 200
#define NBLK_T  (T_LEN * P_TOP / CHUNK)   // 240

typedef float        v4f __attribute__((ext_vector_type(4)));
typedef unsigned int v4u __attribute__((ext_vector_type(4)));

__device__ __forceinline__ unsigned short f32_to_bf16_rne(float f) {
    unsigned int u = __float_as_uint(f);
    unsigned int r = u + 0x7fffu + ((u >> 16) & 1u);
    return (unsigned short)(r >> 16);
}

__device__ __forceinline__ float leaky(float v) {
    return (v > 0.f) ? v : 0.3f * v;
}

// ---------------------------------------------------------------------------
// Kernel 1: pack x [B, T*C] f32 -> 8 slices xs[g][T*C], each uint =
// bf16(x[2g][i]) | bf16(x[2g+1][i])<<16.
// ---------------------------------------------------------------------------
__global__ __launch_bounds__(256) void transpose_pack(const float* __restrict__ x,
                                                      unsigned int* __restrict__ xs) {
    const int i = blockIdx.x * 256 + threadIdx.x;    // [0, TC)
    #pragma unroll
    for (int g = 0; g < NGROUP; ++g) {
        float v0 = x[(size_t)(2 * g)     * TC + i];
        float v1 = x[(size_t)(2 * g + 1) * TC + i];
        unsigned int u = (unsigned int)f32_to_bf16_rne(v0) |
                         ((unsigned int)f32_to_bf16_rne(v1) << 16);
        xs[(size_t)g * TC + i] = u;
    }
}

// ---------------------------------------------------------------------------
// Fused patch compute v5: block owns 256 pairs (main or top layer).
// idx/W loaded into registers ONCE (4 quads/wave, held across phases).
// Loop g=0..7: refill 128 KB LDS slice (2 batches), gather, reduce, write.
// ---------------------------------------------------------------------------
__global__ __launch_bounds__(1024) void patch_fused(
    const unsigned int* __restrict__ xs,     // [8][TC]
    const int*   __restrict__ idx_m, const float* __restrict__ W_m,
    const float* __restrict__ bias_m,
    const int*   __restrict__ idx_t, const float* __restrict__ W_t,
    const float* __restrict__ bias_t,
    float* __restrict__ ws_main,             // [16, S_MAIN, NB_P]
    float* __restrict__ out)                 // [16, T_LEN, 460]
{
    __shared__ unsigned int s_x[TC];         // 128 KB

    const bool is_top = (blockIdx.x >= NBLK_M);
    const int*   idx  = is_top ? idx_t  : idx_m;
    const float* W    = is_top ? W_t    : W_m;
    const float* bias = is_top ? bias_t : bias_m;
    const int    npp  = is_top ? P_TOP  : NB_P;    // pairs per row
    const int pair_lo = (is_top ? (blockIdx.x - NBLK_M) : blockIdx.x) * CHUNK;

    const int wave = threadIdx.x >> 6;       // 0..15
    const int lane = threadIdx.x & 63;
    const int q    = lane & 3;               // pair-in-quad
    const int j    = lane >> 2;              // 0..15, 8 k-elems each

    // ---- Load idx/W/bias for 4 quads into registers (once per block) ----
    int4 ia[4], ib[4];
    v4f  wa[4], wb[4];
    float bv[4];
    int  row[4], pp[4];
    #pragma unroll
    for (int t = 0; t < 4; ++t) {
        const int pair = pair_lo + (wave + t * 16) * 4 + q;
        const int4* i4 = (const int4*)(idx + (size_t)pair * 128 + j * 8);
        const v4f*  w4 = (const v4f*) (W   + (size_t)pair * 128 + j * 8);
        ia[t] = i4[0];
        ib[t] = i4[1];
        wa[t] = w4[0];
        wb[t] = w4[1];
        bv[t] = bias[pair];
        row[t] = pair / npp;          // uniform divisor per block
        pp[t]  = pair - row[t] * npp;
    }

    // ---- 8 phases: fill slice for batches (2g, 2g+1), gather, reduce ----
    for (int g = 0; g < NGROUP; ++g) {
        __syncthreads();     // previous phase's readers done with s_x
        {
            const v4u* src = (const v4u*)(xs + (size_t)g * TC);
            v4u* dl = (v4u*)s_x;
            const int t = threadIdx.x;
            #pragma unroll
            for (int k = 0; k < 8; ++k)
                dl[k * 1024 + t] = src[k * 1024 + t];
        }
        __syncthreads();

        #pragma unroll
        for (int t = 0; t < 4; ++t) {
            float a0 = 0.f, a1 = 0.f;
            #define GATHER(IX, WT)                                        \
                { unsigned int gv = s_x[(IX)];                            \
                  a0 += __uint_as_float(gv << 16)         * (WT);         \
                  a1 += __uint_as_float(gv & 0xffff0000u) * (WT); }
            GATHER(ia[t].x, wa[t].x) GATHER(ia[t].y, wa[t].y)
            GATHER(ia[t].z, wa[t].z) GATHER(ia[t].w, wa[t].w)
            GATHER(ib[t].x, wb[t].x) GATHER(ib[t].y, wb[t].y)
            GATHER(ib[t].z, wb[t].z) GATHER(ib[t].w, wb[t].w)
            #undef GATHER

            #pragma unroll
            for (int m = 4; m <= 32; m <<= 1) {
                a0 += __shfl_xor(a0, m);
                a1 += __shfl_xor(a1, m);
            }

            if (j == 0) {
                const float v0 = leaky(a0 + bv[t]);
                const float v1 = leaky(a1 + bv[t]);
                const int b0 = 2 * g, b1 = 2 * g + 1;
                if (!is_top) {
                    ws_main[((size_t)b0 * S_MAIN + row[t]) * NB_P + pp[t]] = v0;
                    ws_main[((size_t)b1 * S_MAIN + row[t]) * NB_P + pp[t]] = v1;
                } else {
                    out[((size_t)b0 * T_LEN + row[t]) * OUT_CH + NB_P + pp[t]] = v0;
                    out[((size_t)b1 * T_LEN + row[t]) * OUT_CH + NB_P + pp[t]] = v1;
                }
            }
        }
    }
}

// ---------------------------------------------------------------------------
// Upsample main result x8 along time into the output (coalesced).
// out row = 460 floats = 115 float4; main part = first 100 float4.
// ---------------------------------------------------------------------------
__global__ __launch_bounds__(256) void upsample_main(const float* __restrict__ ws_main,
                                                     float* __restrict__ out) {
    const int o4 = blockIdx.x * 256 + threadIdx.x;   // < B*T*100 = 1,638,400
    const int row = o4 / 100;
    const int col = o4 - row * 100;
    const int b = row >> 10;         // /1024
    const int t = row & 1023;
    const int s = t >> 3;            // /STRETCH
    const v4f v = ((const v4f*)ws_main)[((size_t)b * S_MAIN + s) * 100 + col];
    ((v4f*)out)[(size_t)row * 115 + col] = v;
}

// ---------------------------------------------------------------------------
extern "C" void kernel_launch(void* const* d_in, const int* in_sizes, int n_in,
                              void* d_out, int out_size, void* d_ws, size_t ws_size,
                              hipStream_t stream) {
    const float* x      = (const float*)d_in[0];
    const float* W_main = (const float*)d_in[1];
    const float* b_main = (const float*)d_in[2];
    const float* W_top  = (const float*)d_in[3];
    const float* b_top  = (const float*)d_in[4];
    const int*  idx_main = (const int*)d_in[5];
    const int*  idx_top  = (const int*)d_in[6];
    float* out = (float*)d_out;

    unsigned int* xs  = (unsigned int*)d_ws;                          // 1 MB
    float* ws_main    = (float*)((char*)d_ws + (size_t)NGROUP * TC * 4);

    transpose_pack<<<TC / 256, 256, 0, stream>>>(x, xs);

    patch_fused<<<NBLK_M + NBLK_T, 1024, 0, stream>>>(
        xs, idx_main, W_main, b_main, idx_top, W_top, b_top, ws_main, out);

    upsample_main<<<(B_SZ * T_LEN * 100) / 256, 256, 0, stream>>>(ws_main, out);
}